// Round 9
// baseline (329.811 us; speedup 1.0000x reference)
//
#include <hip/hip_runtime.h>
#include <stdint.h>

typedef __attribute__((ext_vector_type(4))) float f32x4;
typedef __attribute__((ext_vector_type(8))) __bf16 bf16x8;

__device__ __forceinline__ unsigned short f2bf(float f) {
  union { float f; unsigned u; } v; v.f = f;
  unsigned r = v.u + 0x7FFF + ((v.u >> 16) & 1);
  return (unsigned short)(r >> 16);
}

__device__ __forceinline__ void g2l16(const void* g, void* l) {
  __builtin_amdgcn_global_load_lds((const __attribute__((address_space(1))) void*)g,
                                   (__attribute__((address_space(3))) void*)l, 16, 0, 0);
}

// ---------------- weight fp32 -> bf16 ----------------
__global__ void cvt_weights(const float* __restrict__ a, const float* __restrict__ p,
                            unsigned short* __restrict__ wa, unsigned short* __restrict__ wp) {
  int i = blockIdx.x * 256 + threadIdx.x;
  if (i < 786432) wa[i] = f2bf(a[i]);
  else wp[i - 786432] = f2bf(p[i - 786432]);
}

// ---------------- fused groupnorm: stats + normalize + transpose ----------------
__global__ __launch_bounds__(256) void gn_fused(
    const float* __restrict__ x, const float* __restrict__ gw, const float* __restrict__ gb,
    unsigned short* __restrict__ xnT) {
  __shared__ float tile[64][65];
  __shared__ float red[8];
  __shared__ float mv[2];
  int bid = blockIdx.x;             // b*8+g
  int g = bid & 7, b = bid >> 3;
  int t = threadIdx.x;
  const float4* p = (const float4*)(x + (size_t)bid * 65536);
  float s = 0.f, ss = 0.f;
  for (int i = t; i < 16384; i += 256) {
    float4 v = p[i];
    s += v.x + v.y + v.z + v.w;
    ss += v.x * v.x + v.y * v.y + v.z * v.z + v.w * v.w;
  }
#pragma unroll
  for (int o = 32; o > 0; o >>= 1) {
    s += __shfl_down(s, o, 64);
    ss += __shfl_down(ss, o, 64);
  }
  int w = t >> 6;
  if ((t & 63) == 0) { red[w] = s; red[4 + w] = ss; }
  __syncthreads();
  if (t == 0) {
    s = red[0] + red[1] + red[2] + red[3];
    ss = red[4] + red[5] + red[6] + red[7];
    float mean = s * (1.f / 65536.f);
    float var = ss * (1.f / 65536.f) - mean * mean;
    mv[0] = mean; mv[1] = rsqrtf(var + 1e-5f);
  }
  __syncthreads();
  float mean = mv[0], rstd = mv[1];
  const float* src = x + (size_t)bid * 65536;
  for (int ch = 0; ch < 16; ch++) {
#pragma unroll
    for (int i = 0; i < 4; i++) {
      int lin = t + i * 256;  // 0..1023
      int c = lin >> 4, p4 = lin & 15;
      float4 v = *(const float4*)(src + (size_t)c * 1024 + ch * 64 + p4 * 4);
      float gg = gw[g * 64 + c] * rstd;
      float bb = gb[g * 64 + c] - mean * gg;
      tile[c][p4 * 4 + 0] = v.x * gg + bb;
      tile[c][p4 * 4 + 1] = v.y * gg + bb;
      tile[c][p4 * 4 + 2] = v.z * gg + bb;
      tile[c][p4 * 4 + 3] = v.w * gg + bb;
    }
    __syncthreads();
    unsigned short* dst = xnT + ((size_t)b * 1024 + ch * 64) * 512 + g * 64;
#pragma unroll
    for (int i = 0; i < 4; i++) {
      int lin = t + i * 256;
      int pp = lin >> 4, cq = lin & 15;
      ushort4 o;
      o.x = f2bf(tile[cq * 4 + 0][pp]);
      o.y = f2bf(tile[cq * 4 + 1][pp]);
      o.z = f2bf(tile[cq * 4 + 2][pp]);
      o.w = f2bf(tile[cq * 4 + 3][pp]);
      *(ushort4*)(dst + (size_t)pp * 512 + cq * 4) = o;
    }
    __syncthreads();
  }
}

// ---------------- generic bf16 B^T GEMM: C[m,n] = sum_k A[m,k]*B[n,k] ----------------
// EPI: 0=none, 1=+bias[n], 2=+bias[m], 3=+bias[m]+res
template <int EPI, bool OUT_BF16>
__global__ __launch_bounds__(256) void gemm_bt(
    const unsigned short* __restrict__ A, int lda, long long sA,
    const unsigned short* __restrict__ B, int ldb, long long sB,
    void* __restrict__ Cv, int ldc, long long sC,
    const float* __restrict__ bias,
    const float* __restrict__ res, long long sRes,
    int M, int N, int K, int mt, int nt) {
  __shared__ __align__(16) unsigned short As[128 * 32];
  __shared__ __align__(16) unsigned short Bs[128 * 32];
  int bid = blockIdx.x;
  int per = mt * nt;
  int b = bid / per;
  int r = bid % per;
  int mi = r / nt, ni = r % nt;
  int t = threadIdx.x;
  int l = t & 63, w = t >> 6;
  int wm = w >> 1, wn = w & 1;
  int fr = l & 15;
  int fk = (l >> 4) << 3;
  const unsigned short* Ab = A + (size_t)b * sA + (size_t)(mi * 128) * lda;
  const unsigned short* Bb = B + (size_t)b * sB + (size_t)(ni * 128) * ldb;
  int sr = t >> 2, sk = (t & 3) << 3;
  const unsigned short* gA = Ab + (size_t)sr * lda + sk;
  const unsigned short* gB = Bb + (size_t)sr * ldb + sk;
  unsigned short* lA = As + w * 512;  // wave-uniform LDS dest
  unsigned short* lB = Bs + w * 512;
  const unsigned short* ra = As + (wm * 64 + fr) * 32 + fk;
  const unsigned short* rb = Bs + (wn * 64 + fr) * 32 + fk;
  f32x4 acc[4][4] = {};
  for (int k0 = 0; k0 < K; k0 += 32) {
    g2l16(gA, lA);
    g2l16(gA + (size_t)64 * lda, lA + 2048);
    g2l16(gB, lB);
    g2l16(gB + (size_t)64 * ldb, lB + 2048);
    gA += 32; gB += 32;
    __syncthreads();
    bf16x8 af[4], bv[4];
#pragma unroll
    for (int i = 0; i < 4; i++) af[i] = *(const bf16x8*)(ra + i * 512);
#pragma unroll
    for (int j = 0; j < 4; j++) bv[j] = *(const bf16x8*)(rb + j * 512);
#pragma unroll
    for (int i = 0; i < 4; i++)
#pragma unroll
      for (int j = 0; j < 4; j++)
        acc[i][j] = __builtin_amdgcn_mfma_f32_16x16x32_bf16(af[i], bv[j], acc[i][j], 0, 0, 0);
    __syncthreads();
  }
  int crow0 = mi * 128 + wm * 64;
  int ccol0 = ni * 128 + wn * 64;
  int lr = (l >> 4) << 2;
  int lc = l & 15;
#pragma unroll
  for (int i = 0; i < 4; i++) {
#pragma unroll
    for (int j = 0; j < 4; j++) {
      int col = ccol0 + j * 16 + lc;
      float bn = (EPI == 1) ? bias[col] : 0.0f;
#pragma unroll
      for (int e = 0; e < 4; e++) {
        int row = crow0 + i * 16 + lr + e;
        float v = acc[i][j][e];
        if (EPI == 1) v += bn;
        if (EPI == 2 || EPI == 3) v += bias[row];
        if (EPI == 3) v += res[(size_t)b * sRes + (size_t)row * ldc + col];
        size_t o = (size_t)b * sC + (size_t)row * ldc + col;
        if (OUT_BF16) ((unsigned short*)Cv)[o] = f2bf(v);
        else ((float*)Cv)[o] = v;
      }
    }
  }
}

// ---------------- flash attention v5b: in-register softmax, no Slds, 2 light barriers/jt ----
// grid 256 (b, i-tile of 64 rows), 512 threads (8 waves).
// qkT[b][p][0..511]=Q, [512..1023]=K ; vbuf[b][c][p] ; obuf[b][p][c] bf16
// Wave w: S stripe cols w*16..+15 (rows = all 64, in sacc regs), PV d-slice w*64..+63.
// Stats: per-stripe row-max/sum -> tiny LDS tables; every wave redundantly computes the
// identical global m/l update in REGISTERS (mrun/lrun) -> no shared running stats, no race.
__global__ __launch_bounds__(512, 2) void flash_attn(
    const unsigned short* __restrict__ qkT, const unsigned short* __restrict__ vbuf,
    unsigned short* __restrict__ obuf) {
  __shared__ __align__(16) unsigned short Qs[64 * 520];     // 66.6 KB (1040B rows)
  __shared__ __align__(16) unsigned short Plds[2][64 * 136];// 2 x 17.4 KB (272B rows: 128 data + 8 pad)
  __shared__ __align__(16) float mtab[2][8][64];            // 2 x 2 KB
  __shared__ __align__(16) float ltab[2][8][64];            // 2 x 2 KB

  const float SC = 0.04419417382415922f;  // 1/sqrt(512)
  int bid = blockIdx.x;
  int logical = (bid & 7) * 32 + (bid >> 3);  // 2 batches per XCD -> K+V L2-resident
  int b = logical >> 4, it = logical & 15;
  int i0 = it * 64;
  int tid = threadIdx.x;
  int l = tid & 63, w = tid >> 6;
  int fr = l & 15, fq = l >> 4;
  int d0 = w * 64;

  const size_t bq = (size_t)b * 1048576;
  const size_t bv = (size_t)b * 524288;

  // ---- stage Q once ----
  {
    const unsigned short* qsrc = qkT + bq + (size_t)i0 * 1024 + l * 8;
#pragma unroll
    for (int i = 0; i < 8; i++) {
      int row = i * 8 + w;
      g2l16(qsrc + (size_t)row * 1024, (char*)Qs + row * 1040);
    }
  }
  __syncthreads();  // drains vmcnt -> Q ready

  f32x4 acc[4][4] = {};
  f32x4 mrun[4], lrun[4];
#pragma unroll
  for (int mi = 0; mi < 4; mi++) {
    mrun[mi] = f32x4{-3e38f, -3e38f, -3e38f, -3e38f};
    lrun[mi] = f32x4{0.f, 0.f, 0.f, 0.f};
  }

  const unsigned short* kg = qkT + bq + 512 + (size_t)(w * 16 + fr) * 1024 + fq * 8;
  const unsigned short* vg = vbuf + bv + (size_t)(d0 + fr) * 1024 + fq * 8;

#pragma unroll 1
  for (int jt = 0; jt < 8; jt++) {
    int buf = jt & 1;
    // ---- pin V loads early: consumed only after B2, latency hides under S+softmax ----
    const unsigned short* vgj = vg + jt * 128;
    bf16x8 vf[16];
#pragma unroll
    for (int nj = 0; nj < 4; nj++)
#pragma unroll
      for (int kp = 0; kp < 4; kp++)
        vf[nj * 4 + kp] = *(const bf16x8*)(vgj + nj * 16384 + kp * 32);
    __builtin_amdgcn_sched_barrier(0);  // forbid sinking V issue into/past S phase

    // ---- S phase: 4 m-frags x wave stripe; Q from LDS, K from L2 ----
    const unsigned short* kgj = kg + (size_t)jt * 131072;
    bf16x8 kf[16];
#pragma unroll
    for (int ks = 0; ks < 16; ks++) kf[ks] = *(const bf16x8*)(kgj + ks * 32);
    f32x4 sacc[4] = {};
#pragma unroll
    for (int ks = 0; ks < 16; ks++) {
#pragma unroll
      for (int mi = 0; mi < 4; mi++) {
        bf16x8 qa = *(const bf16x8*)((const char*)Qs + (mi * 16 + fr) * 1040 + (ks * 4 + fq) * 16);
        sacc[mi] = __builtin_amdgcn_mfma_f32_16x16x32_bf16(qa, kf[ks], sacc[mi], 0, 0, 0);
      }
    }

    // ---- per-stripe row max (reduce over the 16 col-lanes) ----
#pragma unroll
    for (int mi = 0; mi < 4; mi++) {
      f32x4 v = sacc[mi];
#pragma unroll
      for (int mask = 1; mask < 16; mask <<= 1)
#pragma unroll
        for (int e = 0; e < 4; e++) v[e] = fmaxf(v[e], __shfl_xor(v[e], mask, 64));
      if (fr == 0) *(f32x4*)&mtab[buf][w][mi * 16 + fq * 4] = v;
    }
    asm volatile("s_waitcnt lgkmcnt(0)" ::: "memory");
    __builtin_amdgcn_s_barrier();  // B1: m-parts visible (V loads stay in flight)
    __builtin_amdgcn_sched_barrier(0);

    // ---- global mnew (identical in every wave), P=exp in regs, l-parts ----
    f32x4 alpha[4];
#pragma unroll
    for (int mi = 0; mi < 4; mi++) {
      f32x4 mm = mrun[mi];
#pragma unroll
      for (int s = 0; s < 8; s++) {
        f32x4 ms = *(const f32x4*)&mtab[buf][s][mi * 16 + fq * 4];
#pragma unroll
        for (int e = 0; e < 4; e++) mm[e] = fmaxf(mm[e], ms[e]);
      }
#pragma unroll
      for (int e = 0; e < 4; e++) alpha[mi][e] = __expf((mrun[mi][e] - mm[e]) * SC);
      // p = exp((S - mnew)*SC); stripe sum over col-lanes
      f32x4 p;
#pragma unroll
      for (int e = 0; e < 4; e++) p[e] = __expf((sacc[mi][e] - mm[e]) * SC);
      sacc[mi] = p;
      mrun[mi] = mm;
      f32x4 sum = p;
#pragma unroll
      for (int mask = 1; mask < 16; mask <<= 1)
#pragma unroll
        for (int e = 0; e < 4; e++) sum[e] += __shfl_xor(sum[e], mask, 64);
      if (fr == 0) *(f32x4*)&ltab[buf][w][mi * 16 + fq * 4] = sum;
    }
    // ---- write P bf16: row = mi*16+fq*4+e, col = w*16+fr ----
    {
      unsigned short* pb = &Plds[buf][0] + (fq * 4) * 136 + w * 16 + fr;
#pragma unroll
      for (int mi = 0; mi < 4; mi++)
#pragma unroll
        for (int e = 0; e < 4; e++)
          pb[(mi * 16 + e) * 136] = f2bf(sacc[mi][e]);
    }
    asm volatile("s_waitcnt lgkmcnt(0)" ::: "memory");
    __builtin_amdgcn_s_barrier();  // B2: P + l-parts visible
    __builtin_amdgcn_sched_barrier(0);

    // ---- lrun update (all parts already on mnew scale) + acc rescale ----
#pragma unroll
    for (int mi = 0; mi < 4; mi++) {
      f32x4 ls = {0.f, 0.f, 0.f, 0.f};
#pragma unroll
      for (int s = 0; s < 8; s++) {
        f32x4 lv = *(const f32x4*)&ltab[buf][s][mi * 16 + fq * 4];
#pragma unroll
        for (int e = 0; e < 4; e++) ls[e] += lv[e];
      }
#pragma unroll
      for (int e = 0; e < 4; e++) lrun[mi][e] = lrun[mi][e] * alpha[mi][e] + ls[e];
#pragma unroll
      for (int nj = 0; nj < 4; nj++) acc[mi][nj] *= alpha[mi];
    }
    // ---- PV: 4 m x 4 n x 4 kp; P from LDS (row-major [64][136]), V from regs ----
#pragma unroll
    for (int kp = 0; kp < 4; kp++) {
      bf16x8 pf[4];
#pragma unroll
      for (int mi = 0; mi < 4; mi++)
        pf[mi] = *(const bf16x8*)(&Plds[buf][0] + (mi * 16 + fr) * 136 + kp * 32 + fq * 8);
#pragma unroll
      for (int nj = 0; nj < 4; nj++)
#pragma unroll
        for (int mi = 0; mi < 4; mi++)
          acc[mi][nj] = __builtin_amdgcn_mfma_f32_16x16x32_bf16(pf[mi], vf[nj * 4 + kp], acc[mi][nj], 0, 0, 0);
    }
  }

  // ---- epilogue: O /= l (from regs), store bf16 ----
  unsigned short* ob = obuf + bv + (size_t)i0 * 512 + d0 + fr;
#pragma unroll
  for (int mi = 0; mi < 4; mi++) {
    f32x4 linv;
#pragma unroll
    for (int e = 0; e < 4; e++) linv[e] = 1.0f / lrun[mi][e];
#pragma unroll
    for (int nj = 0; nj < 4; nj++)
#pragma unroll
      for (int e = 0; e < 4; e++) {
        int row = mi * 16 + fq * 4 + e;
        ob[(size_t)row * 512 + nj * 16] = f2bf(acc[mi][nj][e] * linv[e]);
      }
  }
}

extern "C" void kernel_launch(void* const* d_in, const int* in_sizes, int n_in,
                              void* d_out, int out_size, void* d_ws, size_t ws_size,
                              hipStream_t stream) {
  const float* x = (const float*)d_in[0];
  const float* norm_w = (const float*)d_in[1];
  const float* norm_b = (const float*)d_in[2];
  const float* qkv_w = (const float*)d_in[3];
  const float* qkv_b = (const float*)d_in[4];
  const float* proj_w = (const float*)d_in[5];
  const float* proj_b = (const float*)d_in[6];
  float* out = (float*)d_out;
  char* ws = (char*)d_ws;

  size_t off = 0;
  auto alloc = [&](size_t bytes) {
    off = (off + 255) & ~(size_t)255;
    size_t r = off; off += bytes; return r;
  };
  unsigned short* wqkv  = (unsigned short*)(ws + alloc((size_t)1536 * 512 * 2));
  unsigned short* wproj = (unsigned short*)(ws + alloc((size_t)512 * 512 * 2));
  unsigned short* xnT   = (unsigned short*)(ws + alloc((size_t)16 * 1024 * 512 * 2));
  unsigned short* qkT   = (unsigned short*)(ws + alloc((size_t)16 * 1024 * 1024 * 2));
  unsigned short* vbuf  = (unsigned short*)(ws + alloc((size_t)16 * 512 * 1024 * 2));
  unsigned short* obuf  = (unsigned short*)(ws + alloc((size_t)16 * 1024 * 512 * 2));

  cvt_weights<<<4096, 256, 0, stream>>>(qkv_w, proj_w, wqkv, wproj);
  gn_fused<<<128, 256, 0, stream>>>(x, norm_w, norm_b, xnT);

  // GEMM1: qkT[b][p][o] = sum_c xnT[b][p][c] * wqkv[o][c] + qkv_b[o], o in [0,1024)
  gemm_bt<1, true><<<1024, 256, 0, stream>>>(
      xnT, 512, 1024LL * 512, wqkv, 512, 0,
      qkT, 1024, 1024LL * 1024, qkv_b, nullptr, 0, 1024, 1024, 512, 8, 8);

  // GEMM2: v[b][c][p] = sum_cc wv[c][cc] * xnT[b][p][cc] + qkv_b[1024+c]
  gemm_bt<2, true><<<512, 256, 0, stream>>>(
      wqkv + (size_t)1024 * 512, 512, 0, xnT, 512, 1024LL * 512,
      vbuf, 1024, 512LL * 1024, qkv_b + 1024, nullptr, 0, 512, 1024, 512, 4, 8);

  // fused attention: obuf[b][p][c] = softmax(Q K^T / sqrt(512)) V
  flash_attn<<<256, 512, 0, stream>>>(qkT, vbuf, obuf);

  // GEMM5: out[b][o][p] = sum_c wproj[o][c] * obuf[b][p][c] + proj_b[o] + x[b][o][p]
  gemm_bt<3, false><<<512, 256, 0, stream>>>(
      wproj, 512, 0, obuf, 512, 1024LL * 512,
      out, 1024, 512LL * 1024, proj_b, x, 512LL * 1024, 512, 1024, 512, 4, 8);
}